// Round 10
// baseline (351.187 us; speedup 1.0000x reference)
//
#include <hip/hip_runtime.h>

#define N_NODES 50000
#define N_EDGES 1600000
#define ET (N_EDGES + N_NODES)   // edges + self-loops
#define DF 128                   // feature / hidden dim
#define SLOPE 0.2f

#define NB 196        // coarse buckets: dst >> 8 (50000/256)
#define BCAP 10240    // slots per bucket (avg 8448, sigma ~92 -> +19 sigma)
#define P1_CHUNK 4096 // edges per bin_pass block (16 per thread)

typedef __attribute__((ext_vector_type(8))) short bf16x8;      // 8 bf16 (4 VGPRs)
typedef __attribute__((ext_vector_type(4))) float floatx4;     // MFMA C/D
typedef __attribute__((ext_vector_type(8))) _Float16 half8;    // 8 fp16 (16 B)
typedef __attribute__((ext_vector_type(2))) _Float16 half2v;   // fdot2 operand

__device__ inline unsigned short f2bf(float v) {               // RNE fp32->bf16
    unsigned int u = __float_as_uint(v);
    u += 0x7FFF + ((u >> 16) & 1);
    return (unsigned short)(u >> 16);
}
__device__ inline void splitbf(float v, unsigned short& h, unsigned short& l) {
    h = f2bf(v);
    float hf = __uint_as_float((unsigned int)h << 16);
    l = f2bf(v - hf);   // residual; hi+lo carries ~16-17 mantissa bits
}

// ---------------------------------------------------------------------------
// One-time W prep: split each 128x128 W (layout [k][c]) into hi/lo bf16,
// stored TRANSPOSED as [c][k]. blockIdx.y = matrix {W1l, W1r, W2l, W2r}.
// Block (0,0) also zeroes g_count (folds the old memset dispatch).
// ---------------------------------------------------------------------------
__global__ __launch_bounds__(256) void wconv4(
    const float* __restrict__ W0, const float* __restrict__ W1,
    const float* __restrict__ W2, const float* __restrict__ W3,
    unsigned short* __restrict__ Wh, unsigned short* __restrict__ Wl,
    int* __restrict__ g_count)
{
    if (blockIdx.x == 0 && blockIdx.y == 0) g_count[threadIdx.x] = 0;
    const int m = blockIdx.y;
    const float* W = (m == 0) ? W0 : (m == 1) ? W1 : (m == 2) ? W2 : W3;
    int idx = blockIdx.x * 256 + threadIdx.x;   // 0..16383
    int c = idx >> 7, k = idx & 127;
    float v = W[k * 128 + c];
    unsigned short h, l;
    splitbf(v, h, l);
    Wh[(size_t)m * 16384 + c * 128 + k] = h;
    Wl[(size_t)m * 16384 + c * 128 + k] = l;
}

// ---------------------------------------------------------------------------
// Split-bf16 MFMA GEMM, L+R merged (unchanged from R9).
// outL fp16 pair-major [2][M][64]; outR fp32 pair-major [2][M][64].
// ---------------------------------------------------------------------------
__global__ __launch_bounds__(256) void gemm_mfma(
    const float* __restrict__ X,
    const unsigned short* __restrict__ WhL, const unsigned short* __restrict__ WlL,
    const unsigned short* __restrict__ WhR, const unsigned short* __restrict__ WlR,
    _Float16* __restrict__ outL, float* __restrict__ outR, int M)
{
    __shared__ unsigned short xh[64 * 40], xl[64 * 40];
    __shared__ unsigned short whL[128 * 40], wlL[128 * 40];
    __shared__ unsigned short whR[128 * 40], wlR[128 * 40];

    const int t = threadIdx.x;
    const int row0 = blockIdx.x * 64;
    const int lane = t & 63, wv = t >> 6;
    const int lm = lane & 15, quad = lane >> 4;
    const int m0 = wv * 16;

    floatx4 accL[8], accR[8];
#pragma unroll
    for (int i = 0; i < 8; i++) { accL[i] = (floatx4)0.f; accR[i] = (floatx4)0.f; }

    const int sr = t >> 2;
    const int sc = (t & 3) * 8;
    const int wn = t >> 1;
    const int wkh = (t & 1) * 16;

    for (int kb = 0; kb < 128; kb += 32) {
        int xrow = row0 + sr; if (xrow >= M) xrow = M - 1;
        const float* xp = X + (size_t)xrow * DF + kb + sc;
        float4 v0 = *(const float4*)(xp);
        float4 v1 = *(const float4*)(xp + 4);
        ushort4 h0, h1, l0, l1;
        splitbf(v0.x, h0.x, l0.x); splitbf(v0.y, h0.y, l0.y);
        splitbf(v0.z, h0.z, l0.z); splitbf(v0.w, h0.w, l0.w);
        splitbf(v1.x, h1.x, l1.x); splitbf(v1.y, h1.y, l1.y);
        splitbf(v1.z, h1.z, l1.z); splitbf(v1.w, h1.w, l1.w);
        *(ushort4*)&xh[sr * 40 + sc]     = h0;
        *(ushort4*)&xh[sr * 40 + sc + 4] = h1;
        *(ushort4*)&xl[sr * 40 + sc]     = l0;
        *(ushort4*)&xl[sr * 40 + sc + 4] = l1;

        const size_t wofs = (size_t)wn * 128 + kb + wkh;
        {
            const uint4* p = (const uint4*)(WhL + wofs);
            uint4 a = p[0], b = p[1];
            *(uint4*)&whL[wn * 40 + wkh] = a; *(uint4*)&whL[wn * 40 + wkh + 8] = b;
        }
        {
            const uint4* p = (const uint4*)(WlL + wofs);
            uint4 a = p[0], b = p[1];
            *(uint4*)&wlL[wn * 40 + wkh] = a; *(uint4*)&wlL[wn * 40 + wkh + 8] = b;
        }
        {
            const uint4* p = (const uint4*)(WhR + wofs);
            uint4 a = p[0], b = p[1];
            *(uint4*)&whR[wn * 40 + wkh] = a; *(uint4*)&whR[wn * 40 + wkh + 8] = b;
        }
        {
            const uint4* p = (const uint4*)(WlR + wofs);
            uint4 a = p[0], b = p[1];
            *(uint4*)&wlR[wn * 40 + wkh] = a; *(uint4*)&wlR[wn * 40 + wkh + 8] = b;
        }
        __syncthreads();

        bf16x8 ahf = *(const bf16x8*)&xh[(m0 + lm) * 40 + quad * 8];
        bf16x8 alf = *(const bf16x8*)&xl[(m0 + lm) * 40 + quad * 8];
#pragma unroll
        for (int nt = 0; nt < 8; nt++) {
            const int bofs = (nt * 16 + lm) * 40 + quad * 8;
            bf16x8 bh = *(const bf16x8*)&whL[bofs];
            bf16x8 bl = *(const bf16x8*)&wlL[bofs];
            accL[nt] = __builtin_amdgcn_mfma_f32_16x16x32_bf16(ahf, bh, accL[nt], 0, 0, 0);
            accL[nt] = __builtin_amdgcn_mfma_f32_16x16x32_bf16(ahf, bl, accL[nt], 0, 0, 0);
            accL[nt] = __builtin_amdgcn_mfma_f32_16x16x32_bf16(alf, bh, accL[nt], 0, 0, 0);
            bf16x8 ch = *(const bf16x8*)&whR[bofs];
            bf16x8 cl = *(const bf16x8*)&wlR[bofs];
            accR[nt] = __builtin_amdgcn_mfma_f32_16x16x32_bf16(ahf, ch, accR[nt], 0, 0, 0);
            accR[nt] = __builtin_amdgcn_mfma_f32_16x16x32_bf16(ahf, cl, accR[nt], 0, 0, 0);
            accR[nt] = __builtin_amdgcn_mfma_f32_16x16x32_bf16(alf, ch, accR[nt], 0, 0, 0);
        }
        __syncthreads();
    }

#pragma unroll
    for (int nt = 0; nt < 8; nt++) {
        int colpair = nt >> 2;
        int coloff  = (nt & 3) * 16 + lm;
#pragma unroll
        for (int r = 0; r < 4; r++) {
            int gr = row0 + m0 + quad * 4 + r;
            if (gr < M) {
                size_t o = ((size_t)colpair * M + gr) * 64 + coloff;
                outL[o] = (_Float16)accL[nt][r];
                outR[o] = accR[nt][r];
            }
        }
    }
}

// ---------------------------------------------------------------------------
// CSR build, two-level bucket sort (unchanged).
// ---------------------------------------------------------------------------
__global__ __launch_bounds__(256) void bin_pass(const int* __restrict__ ei,
                                                int* __restrict__ g_count,
                                                int* __restrict__ bucket_mem)
{
    __shared__ int cnt[NB], base[NB], cnt2[NB];
    const int tid = threadIdx.x;
    for (int i = tid; i < NB; i += 256) { cnt[i] = 0; cnt2[i] = 0; }
    __syncthreads();

    const int e0 = blockIdx.x * P1_CHUNK;
    int srcv[16], dstv[16];
#pragma unroll
    for (int i = 0; i < 16; i++) {
        int eid = e0 + i * 256 + tid;   // coalesced
        int s = 0, d = -1;
        if (eid < ET) {
            if (eid < N_EDGES) { s = ei[eid]; d = ei[N_EDGES + eid]; }
            else               { s = d = eid - N_EDGES; }
        }
        srcv[i] = s; dstv[i] = d;
        if (d >= 0) atomicAdd(&cnt[d >> 8], 1);
    }
    __syncthreads();
    for (int i = tid; i < NB; i += 256)
        base[i] = (cnt[i] > 0) ? atomicAdd(&g_count[i], cnt[i]) : 0;
    __syncthreads();
#pragma unroll
    for (int i = 0; i < 16; i++) {
        int d = dstv[i];
        if (d >= 0) {
            int b = d >> 8;
            int r = atomicAdd(&cnt2[b], 1);
            int slot = base[b] + r;
            if (slot < BCAP)
                bucket_mem[(size_t)b * BCAP + slot] =
                    (srcv[i] & 0xFFFF) | ((d & 255) << 16);
        }
    }
}

__global__ __launch_bounds__(256) void csr_pass(const int* __restrict__ g_count,
                                                const int* __restrict__ bucket_mem,
                                                int* __restrict__ row_ptr,
                                                unsigned short* __restrict__ csr_src)
{
    __shared__ int sh_edges[BCAP];
    __shared__ int hist[256], offs[256], excl[256], cnt2[256];
    __shared__ int gsc[256];
    const int b = blockIdx.x, tid = threadIdx.x;

    gsc[tid] = (tid < NB) ? g_count[tid] : 0;
    __syncthreads();
    for (int d = 1; d < 256; d <<= 1) {
        int x = (tid >= d) ? gsc[tid - d] : 0;
        __syncthreads();
        gsc[tid] += x;
        __syncthreads();
    }
    const int base_csr = (b > 0) ? gsc[b - 1] : 0;

    int m = g_count[b]; if (m > BCAP) m = BCAP;
    hist[tid] = 0; cnt2[tid] = 0;
    __syncthreads();
    const int* bm = bucket_mem + (size_t)b * BCAP;
    for (int i = tid; i < m; i += 256) {
        int p = bm[i];
        sh_edges[i] = p;
        atomicAdd(&hist[(p >> 16) & 255], 1);
    }
    __syncthreads();
    offs[tid] = hist[tid]; __syncthreads();
    for (int d = 1; d < 256; d <<= 1) {
        int x = (tid >= d) ? offs[tid - d] : 0;
        __syncthreads();
        offs[tid] += x;
        __syncthreads();
    }
    excl[tid] = offs[tid] - hist[tid];
    const int node0 = b << 8;
    if (node0 + tid < N_NODES) row_ptr[node0 + tid] = base_csr + excl[tid];
    if (b == 0 && tid == 0) row_ptr[N_NODES] = ET;
    __syncthreads();
    for (int i = tid; i < m; i += 256) {
        int p = sh_edges[i];
        int dl = (p >> 16) & 255;
        int r = atomicAdd(&cnt2[dl], 1);
        csr_src[base_csr + excl[dl] + r] = (unsigned short)(p & 0xFFFF);
    }
}

// ---------------------------------------------------------------------------
// Head-PAIR fused scores + softmax + aggregate, packed-fp16 logit math.
// One wave per (node, pair); 8 lanes/edge, 8 ch/lane, 8 edges/iter.
// Per iter: direct same-address csr_src load (HW broadcast, no bpermute),
// half8 gather, v_pk_add/mul/max_f16 msg+leaky, v_dot2_f32_f16 logits,
// fp32 accumulate. out standard [N][128] fp32.
// ---------------------------------------------------------------------------
__global__ __launch_bounds__(256) void fused_agg(
    const _Float16* __restrict__ XL, const float* __restrict__ XR,
    const int* __restrict__ row_ptr, const unsigned short* __restrict__ csr_src,
    const float* __restrict__ att, const float* __restrict__ bias,
    float* __restrict__ out)
{
    const int t = threadIdx.x;
    const int wave = t >> 6, l = t & 63;
    const int g = l >> 3, gl = l & 7;        // edge group 0..7, lane in group
    const int hp = blockIdx.y;               // head pair
    const int n = blockIdx.x * 4 + wave;
    if (n >= N_NODES) return;
    const int beg = row_ptr[n], end = row_ptr[n + 1];

    const _Float16* xlp = XL + (size_t)hp * N_NODES * 64;
    const int c0 = gl * 8;                   // channel within pair (0..56)
    const float* xrp = XR + ((size_t)hp * N_NODES + n) * 64 + c0;
    float4 xr0 = *(const float4*)(xrp);
    float4 xr1 = *(const float4*)(xrp + 4);
    float4 at0 = *(const float4*)(att + hp * 64 + c0);
    float4 at1 = *(const float4*)(att + hp * 64 + c0 + 4);

    half8 xrh = { (_Float16)xr0.x, (_Float16)xr0.y, (_Float16)xr0.z, (_Float16)xr0.w,
                  (_Float16)xr1.x, (_Float16)xr1.y, (_Float16)xr1.z, (_Float16)xr1.w };
    half2v a01 = { (_Float16)at0.x, (_Float16)at0.y };
    half2v a23 = { (_Float16)at0.z, (_Float16)at0.w };
    half2v a45 = { (_Float16)at1.x, (_Float16)at1.y };
    half2v a67 = { (_Float16)at1.z, (_Float16)at1.w };
    const half8 slp = { (_Float16)SLOPE, (_Float16)SLOPE, (_Float16)SLOPE, (_Float16)SLOPE,
                        (_Float16)SLOPE, (_Float16)SLOPE, (_Float16)SLOPE, (_Float16)SLOPE };

    float a0 = 0.f, a1 = 0.f, a2 = 0.f, a3 = 0.f;
    float a4 = 0.f, a5 = 0.f, a6 = 0.f, a7 = 0.f, den = 0.f;

    for (int j = beg; j < end; j += 8) {
        int eidx = j + g;
        int s = 0;
        if (eidx < end) s = csr_src[eidx];   // 8 lanes same addr -> HW broadcast
        half8 hv = *(const half8*)(xlp + (size_t)s * 64 + c0);
        half8 msg = hv + xrh;                       // v_pk_add_f16 x4
        half8 lk  = __builtin_elementwise_max(msg, msg * slp);  // pk_mul+pk_max x4
        half2v m01 = { lk[0], lk[1] };
        half2v m23 = { lk[2], lk[3] };
        half2v m45 = { lk[4], lk[5] };
        half2v m67 = { lk[6], lk[7] };
        float p = __builtin_amdgcn_fdot2(m01, a01, 0.f, false);
        p = __builtin_amdgcn_fdot2(m23, a23, p, false);
        p = __builtin_amdgcn_fdot2(m45, a45, p, false);
        p = __builtin_amdgcn_fdot2(m67, a67, p, false);
        // per-head reduce within the 8-lane group: lanes {0-3}=head 2hp, {4-7}=2hp+1
        p += __shfl_xor(p, 1);
        p += __shfl_xor(p, 2);
        float e = (eidx < end) ? __expf(p) : 0.f;
        a0 += e * (float)hv[0]; a1 += e * (float)hv[1];
        a2 += e * (float)hv[2]; a3 += e * (float)hv[3];
        a4 += e * (float)hv[4]; a5 += e * (float)hv[5];
        a6 += e * (float)hv[6]; a7 += e * (float)hv[7];
        den += e;
    }

    // combine the 8 edge-group accumulators (same channels, different edges)
#define CMB(x) x += __shfl_xor(x, 8); x += __shfl_xor(x, 16); x += __shfl_xor(x, 32);
    CMB(a0) CMB(a1) CMB(a2) CMB(a3) CMB(a4) CMB(a5) CMB(a6) CMB(a7) CMB(den)
#undef CMB

    if (g == 0) {
        float inv = 1.f / (den + 1e-16f);
        const float* bp = bias + hp * 64 + c0;
        float4 b0 = *(const float4*)(bp);
        float4 b1 = *(const float4*)(bp + 4);
        float4 o0, o1;
        o0.x = fmaxf(a0 * inv + b0.x, 0.f);
        o0.y = fmaxf(a1 * inv + b0.y, 0.f);
        o0.z = fmaxf(a2 * inv + b0.z, 0.f);
        o0.w = fmaxf(a3 * inv + b0.w, 0.f);
        o1.x = fmaxf(a4 * inv + b1.x, 0.f);
        o1.y = fmaxf(a5 * inv + b1.y, 0.f);
        o1.z = fmaxf(a6 * inv + b1.z, 0.f);
        o1.w = fmaxf(a7 * inv + b1.w, 0.f);
        float* op = out + (size_t)n * DF + hp * 64 + c0;
        *(float4*)(op)     = o0;
        *(float4*)(op + 4) = o1;
    }
}

// ---------------------------------------------------------------------------
extern "C" void kernel_launch(void* const* d_in, const int* in_sizes, int n_in,
                              void* d_out, int out_size, void* d_ws, size_t ws_size,
                              hipStream_t stream)
{
    (void)in_sizes; (void)n_in; (void)out_size; (void)ws_size;

    const float* x    = (const float*)d_in[0];
    const int*   ei   = (const int*)d_in[1];
    const float* W1l  = (const float*)d_in[2];
    const float* W1r  = (const float*)d_in[3];
    const float* att1 = (const float*)d_in[4];
    const float* b1   = (const float*)d_in[5];
    const float* W2l  = (const float*)d_in[6];
    const float* W2r  = (const float*)d_in[7];
    const float* att2 = (const float*)d_in[8];
    const float* b2   = (const float*)d_in[9];
    float* out = (float*)d_out;

    char* ws = (char*)d_ws;
    size_t off = 0;
    const size_t NF = (size_t)N_NODES * DF * sizeof(float);        // 25.6 MB
    _Float16* A = (_Float16*)(ws + off); off += NF / 2;            // xl fp16 pair-major
    float* B  = (float*)(ws + off); off += NF;                     // xr fp32 pair-major
    float* C  = (float*)(ws + off); off += NF;                     // layer-1 out (std)
    int* bucket_mem  = (int*)(ws + off); off += (size_t)NB * BCAP * sizeof(int);
    int* g_count     = (int*)(ws + off); off += 256 * sizeof(int);
    int* row_ptr     = (int*)(ws + off); off += (size_t)(N_NODES + 1) * sizeof(int);
    unsigned short* csr_src = (unsigned short*)(ws + off);
    off += ((size_t)ET * sizeof(unsigned short) + 255) & ~(size_t)255;
    unsigned short* Wh = (unsigned short*)(ws + off); off += 4 * 16384 * sizeof(unsigned short);
    unsigned short* Wl = (unsigned short*)(ws + off); off += 4 * 16384 * sizeof(unsigned short);

    // ---- one-time prep (wconv also zeroes g_count) ----
    wconv4<<<dim3(64, 4), 256, 0, stream>>>(W1l, W1r, W2l, W2r, Wh, Wl, g_count);
    bin_pass<<<(ET + P1_CHUNK - 1) / P1_CHUNK, 256, 0, stream>>>(ei, g_count, bucket_mem);
    csr_pass<<<NB, 256, 0, stream>>>(g_count, bucket_mem, row_ptr, csr_src);

    dim3 gg((N_NODES + 63) / 64);
    dim3 ga((N_NODES + 3) / 4, 2);

    // ---- layer 1 ----
    gemm_mfma<<<gg, 256, 0, stream>>>(x, Wh, Wl, Wh + 16384, Wl + 16384, A, B, N_NODES);
    fused_agg<<<ga, 256, 0, stream>>>(A, B, row_ptr, csr_src, att1, b1, C);

    // ---- layer 2 ----
    gemm_mfma<<<gg, 256, 0, stream>>>(C, Wh + 2 * 16384, Wl + 2 * 16384,
                                      Wh + 3 * 16384, Wl + 3 * 16384, A, B, N_NODES);
    fused_agg<<<ga, 256, 0, stream>>>(A, B, row_ptr, csr_src, att2, b2, out);
}

// Round 11
// 301.930 us; speedup vs baseline: 1.1631x; 1.1631x over previous
//
#include <hip/hip_runtime.h>

#define N_NODES 50000
#define N_EDGES 1600000
#define ET (N_EDGES + N_NODES)   // edges + self-loops
#define DF 128                   // feature / hidden dim
#define SLOPE 0.2f

#define NB 196        // coarse buckets: dst >> 8 (50000/256)
#define BCAP 10240    // slots per bucket (avg 8448, sigma ~92 -> +19 sigma)
#define P1_CHUNK 4096 // edges per bin_pass block (16 per thread)

typedef __attribute__((ext_vector_type(8))) short bf16x8;      // 8 bf16 (4 VGPRs)
typedef __attribute__((ext_vector_type(4))) float floatx4;     // MFMA C/D
typedef __attribute__((ext_vector_type(8))) _Float16 half8;    // 8 fp16 (16 B)
typedef __attribute__((ext_vector_type(2))) _Float16 half2v;   // fdot2 operand

__device__ inline unsigned short f2bf(float v) {               // RNE fp32->bf16
    unsigned int u = __float_as_uint(v);
    u += 0x7FFF + ((u >> 16) & 1);
    return (unsigned short)(u >> 16);
}
__device__ inline void splitbf(float v, unsigned short& h, unsigned short& l) {
    h = f2bf(v);
    float hf = __uint_as_float((unsigned int)h << 16);
    l = f2bf(v - hf);   // residual; hi+lo carries ~16-17 mantissa bits
}

// ---------------------------------------------------------------------------
// CSR pass 1 + W prep fused. Blocks 0..255 additionally split one 256-elem
// chunk of the four 128x128 W matrices into hi/lo bf16, stored transposed
// [c][k]. All blocks bin edges by coarse bucket (dst>>8), packed 4B:
// src | (dst&255)<<16.
// ---------------------------------------------------------------------------
__global__ __launch_bounds__(256) void bin_wconv(
    const int* __restrict__ ei,
    const float* __restrict__ W0, const float* __restrict__ W1,
    const float* __restrict__ W2, const float* __restrict__ W3,
    unsigned short* __restrict__ Wh, unsigned short* __restrict__ Wl,
    int* __restrict__ g_count, int* __restrict__ bucket_mem)
{
    const int tid = threadIdx.x;
    if (blockIdx.x < 256) {          // wconv side-job: 256 blocks x 256 elems
        int idx = blockIdx.x * 256 + tid;       // 0..65535
        int m = idx >> 14, rem = idx & 16383;
        const float* W = (m == 0) ? W0 : (m == 1) ? W1 : (m == 2) ? W2 : W3;
        int c = rem >> 7, k = rem & 127;
        unsigned short h, l;
        splitbf(W[k * 128 + c], h, l);
        Wh[(size_t)m * 16384 + c * 128 + k] = h;
        Wl[(size_t)m * 16384 + c * 128 + k] = l;
    }

    __shared__ int cnt[NB], base[NB], cnt2[NB];
    for (int i = tid; i < NB; i += 256) { cnt[i] = 0; cnt2[i] = 0; }
    __syncthreads();

    const int e0 = blockIdx.x * P1_CHUNK;
    int srcv[16], dstv[16];
#pragma unroll
    for (int i = 0; i < 16; i++) {
        int eid = e0 + i * 256 + tid;   // coalesced
        int s = 0, d = -1;
        if (eid < ET) {
            if (eid < N_EDGES) { s = ei[eid]; d = ei[N_EDGES + eid]; }
            else               { s = d = eid - N_EDGES; }
        }
        srcv[i] = s; dstv[i] = d;
        if (d >= 0) atomicAdd(&cnt[d >> 8], 1);
    }
    __syncthreads();
    for (int i = tid; i < NB; i += 256)
        base[i] = (cnt[i] > 0) ? atomicAdd(&g_count[i], cnt[i]) : 0;
    __syncthreads();
#pragma unroll
    for (int i = 0; i < 16; i++) {
        int d = dstv[i];
        if (d >= 0) {
            int b = d >> 8;
            int r = atomicAdd(&cnt2[b], 1);
            int slot = base[b] + r;
            if (slot < BCAP)
                bucket_mem[(size_t)b * BCAP + slot] =
                    (srcv[i] & 0xFFFF) | ((d & 255) << 16);
        }
    }
}

// Pass 2: one block per bucket (unchanged from R10).
__global__ __launch_bounds__(256) void csr_pass(const int* __restrict__ g_count,
                                                const int* __restrict__ bucket_mem,
                                                int* __restrict__ row_ptr,
                                                unsigned short* __restrict__ csr_src)
{
    __shared__ int sh_edges[BCAP];
    __shared__ int hist[256], offs[256], excl[256], cnt2[256];
    __shared__ int gsc[256];
    const int b = blockIdx.x, tid = threadIdx.x;

    gsc[tid] = (tid < NB) ? g_count[tid] : 0;
    __syncthreads();
    for (int d = 1; d < 256; d <<= 1) {
        int x = (tid >= d) ? gsc[tid - d] : 0;
        __syncthreads();
        gsc[tid] += x;
        __syncthreads();
    }
    const int base_csr = (b > 0) ? gsc[b - 1] : 0;

    int m = g_count[b]; if (m > BCAP) m = BCAP;
    hist[tid] = 0; cnt2[tid] = 0;
    __syncthreads();
    const int* bm = bucket_mem + (size_t)b * BCAP;
    for (int i = tid; i < m; i += 256) {
        int p = bm[i];
        sh_edges[i] = p;
        atomicAdd(&hist[(p >> 16) & 255], 1);
    }
    __syncthreads();
    offs[tid] = hist[tid]; __syncthreads();
    for (int d = 1; d < 256; d <<= 1) {
        int x = (tid >= d) ? offs[tid - d] : 0;
        __syncthreads();
        offs[tid] += x;
        __syncthreads();
    }
    excl[tid] = offs[tid] - hist[tid];
    const int node0 = b << 8;
    if (node0 + tid < N_NODES) row_ptr[node0 + tid] = base_csr + excl[tid];
    if (b == 0 && tid == 0) row_ptr[N_NODES] = ET;
    __syncthreads();
    for (int i = tid; i < m; i += 256) {
        int p = sh_edges[i];
        int dl = (p >> 16) & 255;
        int r = atomicAdd(&cnt2[dl], 1);
        csr_src[base_csr + excl[dl] + r] = (unsigned short)(p & 0xFFFF);
    }
}

// ---------------------------------------------------------------------------
// Split-bf16 MFMA GEMM, L+R merged. Both outputs fp16 standard [M][128]
// (fused_agg converts xr to fp16 anyway -> no extra rounding).
// ---------------------------------------------------------------------------
__global__ __launch_bounds__(256) void gemm_mfma(
    const float* __restrict__ X,
    const unsigned short* __restrict__ WhL, const unsigned short* __restrict__ WlL,
    const unsigned short* __restrict__ WhR, const unsigned short* __restrict__ WlR,
    _Float16* __restrict__ outL, _Float16* __restrict__ outR, int M)
{
    __shared__ unsigned short xh[64 * 40], xl[64 * 40];
    __shared__ unsigned short whL[128 * 40], wlL[128 * 40];
    __shared__ unsigned short whR[128 * 40], wlR[128 * 40];

    const int t = threadIdx.x;
    const int row0 = blockIdx.x * 64;
    const int lane = t & 63, wv = t >> 6;
    const int lm = lane & 15, quad = lane >> 4;
    const int m0 = wv * 16;

    floatx4 accL[8], accR[8];
#pragma unroll
    for (int i = 0; i < 8; i++) { accL[i] = (floatx4)0.f; accR[i] = (floatx4)0.f; }

    const int sr = t >> 2;
    const int sc = (t & 3) * 8;
    const int wn = t >> 1;
    const int wkh = (t & 1) * 16;

    for (int kb = 0; kb < 128; kb += 32) {
        int xrow = row0 + sr; if (xrow >= M) xrow = M - 1;
        const float* xp = X + (size_t)xrow * DF + kb + sc;
        float4 v0 = *(const float4*)(xp);
        float4 v1 = *(const float4*)(xp + 4);
        ushort4 h0, h1, l0, l1;
        splitbf(v0.x, h0.x, l0.x); splitbf(v0.y, h0.y, l0.y);
        splitbf(v0.z, h0.z, l0.z); splitbf(v0.w, h0.w, l0.w);
        splitbf(v1.x, h1.x, l1.x); splitbf(v1.y, h1.y, l1.y);
        splitbf(v1.z, h1.z, l1.z); splitbf(v1.w, h1.w, l1.w);
        *(ushort4*)&xh[sr * 40 + sc]     = h0;
        *(ushort4*)&xh[sr * 40 + sc + 4] = h1;
        *(ushort4*)&xl[sr * 40 + sc]     = l0;
        *(ushort4*)&xl[sr * 40 + sc + 4] = l1;

        const size_t wofs = (size_t)wn * 128 + kb + wkh;
        {
            const uint4* p = (const uint4*)(WhL + wofs);
            uint4 a = p[0], b = p[1];
            *(uint4*)&whL[wn * 40 + wkh] = a; *(uint4*)&whL[wn * 40 + wkh + 8] = b;
        }
        {
            const uint4* p = (const uint4*)(WlL + wofs);
            uint4 a = p[0], b = p[1];
            *(uint4*)&wlL[wn * 40 + wkh] = a; *(uint4*)&wlL[wn * 40 + wkh + 8] = b;
        }
        {
            const uint4* p = (const uint4*)(WhR + wofs);
            uint4 a = p[0], b = p[1];
            *(uint4*)&whR[wn * 40 + wkh] = a; *(uint4*)&whR[wn * 40 + wkh + 8] = b;
        }
        {
            const uint4* p = (const uint4*)(WlR + wofs);
            uint4 a = p[0], b = p[1];
            *(uint4*)&wlR[wn * 40 + wkh] = a; *(uint4*)&wlR[wn * 40 + wkh + 8] = b;
        }
        __syncthreads();

        bf16x8 ahf = *(const bf16x8*)&xh[(m0 + lm) * 40 + quad * 8];
        bf16x8 alf = *(const bf16x8*)&xl[(m0 + lm) * 40 + quad * 8];
#pragma unroll
        for (int nt = 0; nt < 8; nt++) {
            const int bofs = (nt * 16 + lm) * 40 + quad * 8;
            bf16x8 bh = *(const bf16x8*)&whL[bofs];
            bf16x8 bl = *(const bf16x8*)&wlL[bofs];
            accL[nt] = __builtin_amdgcn_mfma_f32_16x16x32_bf16(ahf, bh, accL[nt], 0, 0, 0);
            accL[nt] = __builtin_amdgcn_mfma_f32_16x16x32_bf16(ahf, bl, accL[nt], 0, 0, 0);
            accL[nt] = __builtin_amdgcn_mfma_f32_16x16x32_bf16(alf, bh, accL[nt], 0, 0, 0);
            bf16x8 ch = *(const bf16x8*)&whR[bofs];
            bf16x8 cl = *(const bf16x8*)&wlR[bofs];
            accR[nt] = __builtin_amdgcn_mfma_f32_16x16x32_bf16(ahf, ch, accR[nt], 0, 0, 0);
            accR[nt] = __builtin_amdgcn_mfma_f32_16x16x32_bf16(ahf, cl, accR[nt], 0, 0, 0);
            accR[nt] = __builtin_amdgcn_mfma_f32_16x16x32_bf16(alf, ch, accR[nt], 0, 0, 0);
        }
        __syncthreads();
    }

#pragma unroll
    for (int nt = 0; nt < 8; nt++) {
        int col = (nt >> 2) * 64 + (nt & 3) * 16 + lm;
#pragma unroll
        for (int r = 0; r < 4; r++) {
            int gr = row0 + m0 + quad * 4 + r;
            if (gr < M) {
                size_t o = (size_t)gr * DF + col;
                outL[o] = (_Float16)accL[nt][r];
                outR[o] = (_Float16)accR[nt][r];
            }
        }
    }
}

// ---------------------------------------------------------------------------
// Full-width fused scores + softmax + aggregate, fp16 gather + packed math.
// One wave per node; 16 lanes/edge (8 fp16 ch/lane over all 128 ch), 4 edges
// per iteration, 1-deep software pipeline (next csr+gather prefetched).
// head = (l&15)>>2; per-head logit via fdot2 + 2-shfl reduce; per-head den
// rides in the lane's own head position. out standard [N][128] fp32.
// ---------------------------------------------------------------------------
__global__ __launch_bounds__(256) void fused_agg(
    const _Float16* __restrict__ XL, const _Float16* __restrict__ XR,
    const int* __restrict__ row_ptr, const unsigned short* __restrict__ csr_src,
    const float* __restrict__ att, const float* __restrict__ bias,
    float* __restrict__ out)
{
    const int t = threadIdx.x;
    const int wave = t >> 6, l = t & 63;
    const int g = l >> 4, gl = l & 15;       // edge group 0..3, lane in group
    const int n = blockIdx.x * 4 + wave;
    if (n >= N_NODES) return;
    const int beg = row_ptr[n], end = row_ptr[n + 1];

    const int c0 = gl * 8;                   // channels c0..c0+7
    half8 xrh = *(const half8*)(XR + (size_t)n * DF + c0);
    float4 at0 = *(const float4*)(att + c0);
    float4 at1 = *(const float4*)(att + c0 + 4);
    half2v a01 = { (_Float16)at0.x, (_Float16)at0.y };
    half2v a23 = { (_Float16)at0.z, (_Float16)at0.w };
    half2v a45 = { (_Float16)at1.x, (_Float16)at1.y };
    half2v a67 = { (_Float16)at1.z, (_Float16)at1.w };
    const half8 slp = { (_Float16)SLOPE, (_Float16)SLOPE, (_Float16)SLOPE, (_Float16)SLOPE,
                        (_Float16)SLOPE, (_Float16)SLOPE, (_Float16)SLOPE, (_Float16)SLOPE };

    float a0 = 0.f, a1 = 0.f, a2 = 0.f, a3 = 0.f;
    float a4 = 0.f, a5 = 0.f, a6 = 0.f, a7 = 0.f, den = 0.f;

    // pipeline prologue: first octet's csr + gather
    int eidx = beg + g;
    int s = (eidx < end) ? csr_src[eidx] : 0;
    half8 hv = *(const half8*)(XL + (size_t)s * DF + c0);

    for (int j = beg; j < end; j += 4) {
        // prefetch next iteration (row-0 fallback keeps it branchless/safe)
        int eidx_n = j + 4 + g;
        int s_n = (eidx_n < end) ? csr_src[eidx_n] : 0;
        half8 hv_n = *(const half8*)(XL + (size_t)s_n * DF + c0);

        half8 msg = hv + xrh;                                   // v_pk_add_f16 x4
        half8 lk  = __builtin_elementwise_max(msg, msg * slp);  // pk_mul+pk_max x4
        half2v m01 = { lk[0], lk[1] };
        half2v m23 = { lk[2], lk[3] };
        half2v m45 = { lk[4], lk[5] };
        half2v m67 = { lk[6], lk[7] };
        float p = __builtin_amdgcn_fdot2(m01, a01, 0.f, false);
        p = __builtin_amdgcn_fdot2(m23, a23, p, false);
        p = __builtin_amdgcn_fdot2(m45, a45, p, false);
        p = __builtin_amdgcn_fdot2(m67, a67, p, false);
        // reduce over the 4 lanes of this head (gl bits 0-1)
        p += __shfl_xor(p, 1);
        p += __shfl_xor(p, 2);
        float e = (j + g < end) ? __expf(p) : 0.f;
        a0 += e * (float)hv[0]; a1 += e * (float)hv[1];
        a2 += e * (float)hv[2]; a3 += e * (float)hv[3];
        a4 += e * (float)hv[4]; a5 += e * (float)hv[5];
        a6 += e * (float)hv[6]; a7 += e * (float)hv[7];
        den += e;

        hv = hv_n;
    }

    // combine the 4 edge-group accumulators (l bits 4-5)
#define CMB(x) x += __shfl_xor(x, 16); x += __shfl_xor(x, 32);
    CMB(a0) CMB(a1) CMB(a2) CMB(a3) CMB(a4) CMB(a5) CMB(a6) CMB(a7) CMB(den)
#undef CMB

    if (g == 0) {
        float inv = 1.f / (den + 1e-16f);     // den is this lane's head's total
        float4 b0 = *(const float4*)(bias + c0);
        float4 b1 = *(const float4*)(bias + c0 + 4);
        float4 o0, o1;
        o0.x = fmaxf(a0 * inv + b0.x, 0.f);
        o0.y = fmaxf(a1 * inv + b0.y, 0.f);
        o0.z = fmaxf(a2 * inv + b0.z, 0.f);
        o0.w = fmaxf(a3 * inv + b0.w, 0.f);
        o1.x = fmaxf(a4 * inv + b1.x, 0.f);
        o1.y = fmaxf(a5 * inv + b1.y, 0.f);
        o1.z = fmaxf(a6 * inv + b1.z, 0.f);
        o1.w = fmaxf(a7 * inv + b1.w, 0.f);
        float* op = out + (size_t)n * DF + c0;
        *(float4*)(op)     = o0;
        *(float4*)(op + 4) = o1;
    }
}

// ---------------------------------------------------------------------------
extern "C" void kernel_launch(void* const* d_in, const int* in_sizes, int n_in,
                              void* d_out, int out_size, void* d_ws, size_t ws_size,
                              hipStream_t stream)
{
    (void)in_sizes; (void)n_in; (void)out_size; (void)ws_size;

    const float* x    = (const float*)d_in[0];
    const int*   ei   = (const int*)d_in[1];
    const float* W1l  = (const float*)d_in[2];
    const float* W1r  = (const float*)d_in[3];
    const float* att1 = (const float*)d_in[4];
    const float* b1   = (const float*)d_in[5];
    const float* W2l  = (const float*)d_in[6];
    const float* W2r  = (const float*)d_in[7];
    const float* att2 = (const float*)d_in[8];
    const float* b2   = (const float*)d_in[9];
    float* out = (float*)d_out;

    char* ws = (char*)d_ws;
    size_t off = 0;
    const size_t NF = (size_t)N_NODES * DF * sizeof(float);        // 25.6 MB
    _Float16* A = (_Float16*)(ws + off); off += NF / 2;            // xl fp16 [N][128]
    _Float16* B = (_Float16*)(ws + off); off += NF / 2;            // xr fp16 [N][128]
    float* C  = (float*)(ws + off); off += NF;                     // layer-1 out (std fp32)
    int* bucket_mem  = (int*)(ws + off); off += (size_t)NB * BCAP * sizeof(int);
    int* g_count     = (int*)(ws + off); off += 256 * sizeof(int);
    int* row_ptr     = (int*)(ws + off); off += (size_t)(N_NODES + 1) * sizeof(int);
    unsigned short* csr_src = (unsigned short*)(ws + off);
    off += ((size_t)ET * sizeof(unsigned short) + 255) & ~(size_t)255;
    unsigned short* Wh = (unsigned short*)(ws + off); off += 4 * 16384 * sizeof(unsigned short);
    unsigned short* Wl = (unsigned short*)(ws + off); off += 4 * 16384 * sizeof(unsigned short);

    // ---- one-time prep ----
    hipMemsetAsync(g_count, 0, 256 * sizeof(int), stream);
    bin_wconv<<<(ET + P1_CHUNK - 1) / P1_CHUNK, 256, 0, stream>>>(
        ei, W1l, W1r, W2l, W2r, Wh, Wl, g_count, bucket_mem);
    csr_pass<<<NB, 256, 0, stream>>>(g_count, bucket_mem, row_ptr, csr_src);

    dim3 gg((N_NODES + 63) / 64);
    dim3 ga((N_NODES + 3) / 4);

    // ---- layer 1 ----
    gemm_mfma<<<gg, 256, 0, stream>>>(x, Wh, Wl, Wh + 16384, Wl + 16384, A, B, N_NODES);
    fused_agg<<<ga, 256, 0, stream>>>(A, B, row_ptr, csr_src, att1, b1, C);

    // ---- layer 2 ----
    gemm_mfma<<<gg, 256, 0, stream>>>(C, Wh + 2 * 16384, Wl + 2 * 16384,
                                      Wh + 3 * 16384, Wl + 3 * 16384, A, B, N_NODES);
    fused_agg<<<ga, 256, 0, stream>>>(A, B, row_ptr, csr_src, att2, b2, out);
}

// Round 12
// 287.138 us; speedup vs baseline: 1.2231x; 1.0515x over previous
//
#include <hip/hip_runtime.h>

#define N_NODES 50000
#define N_EDGES 1600000
#define ET (N_EDGES + N_NODES)   // edges + self-loops
#define DF 128                   // feature / hidden dim
#define SLOPE 0.2f

#define NB 196        // coarse buckets: dst >> 8 (50000/256)
#define BCAP 10240    // slots per bucket (avg 8448, sigma ~92 -> +19 sigma)
#define P1_CHUNK 4096 // edges per bin block (16 per thread)
#define GEMM_BLOCKS ((N_NODES + 63) / 64)            // 782
#define BIN_BLOCKS ((ET + P1_CHUNK - 1) / P1_CHUNK)  // 403

typedef __attribute__((ext_vector_type(8))) short bf16x8;      // 8 bf16 (4 VGPRs)
typedef __attribute__((ext_vector_type(4))) float floatx4;     // MFMA C/D
typedef __attribute__((ext_vector_type(8))) _Float16 half8;    // 8 fp16 (16 B)
typedef __attribute__((ext_vector_type(2))) _Float16 half2v;   // fdot2 operand

__device__ inline unsigned short f2bf(float v) {               // RNE fp32->bf16
    unsigned int u = __float_as_uint(v);
    u += 0x7FFF + ((u >> 16) & 1);
    return (unsigned short)(u >> 16);
}
__device__ inline void splitbf(float v, unsigned short& h, unsigned short& l) {
    h = f2bf(v);
    float hf = __uint_as_float((unsigned int)h << 16);
    l = f2bf(v - hf);   // residual; hi+lo carries ~16-17 mantissa bits
}

__device__ __forceinline__ void load8f(const float* p, float* v) {
    float4 a = *(const float4*)(p);
    float4 b = *(const float4*)(p + 4);
    v[0]=a.x; v[1]=a.y; v[2]=a.z; v[3]=a.w; v[4]=b.x; v[5]=b.y; v[6]=b.z; v[7]=b.w;
}
__device__ __forceinline__ void load8f(const _Float16* p, float* v) {
    half8 h = *(const half8*)(p);
#pragma unroll
    for (int i = 0; i < 8; i++) v[i] = (float)h[i];
}

// ---------------------------------------------------------------------------
// One-time W prep (runs before the mega-kernel; also zeroes g_count).
// Splits the four 128x128 W matrices into hi/lo bf16, transposed [c][k].
// ---------------------------------------------------------------------------
__global__ __launch_bounds__(256) void wconv4(
    const float* __restrict__ W0, const float* __restrict__ W1,
    const float* __restrict__ W2, const float* __restrict__ W3,
    unsigned short* __restrict__ Wh, unsigned short* __restrict__ Wl,
    int* __restrict__ g_count)
{
    if (blockIdx.x == 0) g_count[threadIdx.x] = 0;
    int idx = blockIdx.x * 256 + threadIdx.x;   // 0..65535
    int m = idx >> 14, rem = idx & 16383;
    const float* W = (m == 0) ? W0 : (m == 1) ? W1 : (m == 2) ? W2 : W3;
    int c = rem >> 7, k = rem & 127;
    unsigned short h, l;
    splitbf(W[k * 128 + c], h, l);
    Wh[(size_t)m * 16384 + c * 128 + k] = h;
    Wl[(size_t)m * 16384 + c * 128 + k] = l;
}

// ---------------------------------------------------------------------------
// GEMM body: split-bf16 MFMA, L+R merged, 64-row tile, BK=32, 48 MFMA/K-iter.
// acc += Ah*Bh + Ah*Bl + Al*Bh. Outputs fp16 standard [M][128].
// ---------------------------------------------------------------------------
template<typename T>
__device__ __forceinline__ void gemm_body(
    int bid, const T* __restrict__ X,
    const unsigned short* __restrict__ WhL, const unsigned short* __restrict__ WlL,
    const unsigned short* __restrict__ WhR, const unsigned short* __restrict__ WlR,
    _Float16* __restrict__ outL, _Float16* __restrict__ outR, int M, char* smem_)
{
    unsigned short* xh  = (unsigned short*)smem_;   // 64*40
    unsigned short* xls = xh + 64 * 40;             // 64*40
    unsigned short* whL = xls + 64 * 40;            // 128*40
    unsigned short* wlL = whL + 128 * 40;
    unsigned short* whR = wlL + 128 * 40;
    unsigned short* wlR = whR + 128 * 40;           // total 51,200 B

    const int t = threadIdx.x;
    const int row0 = bid * 64;
    const int lane = t & 63, wv = t >> 6;
    const int lm = lane & 15, quad = lane >> 4;
    const int m0 = wv * 16;

    floatx4 accL[8], accR[8];
#pragma unroll
    for (int i = 0; i < 8; i++) { accL[i] = (floatx4)0.f; accR[i] = (floatx4)0.f; }

    const int sr = t >> 2;          // X stage: row 0..63 (4 thr/row)
    const int sc = (t & 3) * 8;     // X stage: k offset
    const int wn = t >> 1;          // W stage: col 0..127 (2 thr/col)
    const int wkh = (t & 1) * 16;   // W stage: k half

    for (int kb = 0; kb < 128; kb += 32) {
        int xrow = row0 + sr; if (xrow >= M) xrow = M - 1;
        float xv[8];
        load8f(X + (size_t)xrow * DF + kb + sc, xv);
        ushort4 h0, h1, l0, l1;
        splitbf(xv[0], h0.x, l0.x); splitbf(xv[1], h0.y, l0.y);
        splitbf(xv[2], h0.z, l0.z); splitbf(xv[3], h0.w, l0.w);
        splitbf(xv[4], h1.x, l1.x); splitbf(xv[5], h1.y, l1.y);
        splitbf(xv[6], h1.z, l1.z); splitbf(xv[7], h1.w, l1.w);
        *(ushort4*)&xh[sr * 40 + sc]      = h0;
        *(ushort4*)&xh[sr * 40 + sc + 4]  = h1;
        *(ushort4*)&xls[sr * 40 + sc]     = l0;
        *(ushort4*)&xls[sr * 40 + sc + 4] = l1;

        const size_t wofs = (size_t)wn * 128 + kb + wkh;
        {
            const uint4* p = (const uint4*)(WhL + wofs);
            uint4 a = p[0], b = p[1];
            *(uint4*)&whL[wn * 40 + wkh] = a; *(uint4*)&whL[wn * 40 + wkh + 8] = b;
        }
        {
            const uint4* p = (const uint4*)(WlL + wofs);
            uint4 a = p[0], b = p[1];
            *(uint4*)&wlL[wn * 40 + wkh] = a; *(uint4*)&wlL[wn * 40 + wkh + 8] = b;
        }
        {
            const uint4* p = (const uint4*)(WhR + wofs);
            uint4 a = p[0], b = p[1];
            *(uint4*)&whR[wn * 40 + wkh] = a; *(uint4*)&whR[wn * 40 + wkh + 8] = b;
        }
        {
            const uint4* p = (const uint4*)(WlR + wofs);
            uint4 a = p[0], b = p[1];
            *(uint4*)&wlR[wn * 40 + wkh] = a; *(uint4*)&wlR[wn * 40 + wkh + 8] = b;
        }
        __syncthreads();

        bf16x8 ahf = *(const bf16x8*)&xh[(m0 + lm) * 40 + quad * 8];
        bf16x8 alf = *(const bf16x8*)&xls[(m0 + lm) * 40 + quad * 8];
#pragma unroll
        for (int nt = 0; nt < 8; nt++) {
            const int bofs = (nt * 16 + lm) * 40 + quad * 8;
            bf16x8 bh = *(const bf16x8*)&whL[bofs];
            bf16x8 bl = *(const bf16x8*)&wlL[bofs];
            accL[nt] = __builtin_amdgcn_mfma_f32_16x16x32_bf16(ahf, bh, accL[nt], 0, 0, 0);
            accL[nt] = __builtin_amdgcn_mfma_f32_16x16x32_bf16(ahf, bl, accL[nt], 0, 0, 0);
            accL[nt] = __builtin_amdgcn_mfma_f32_16x16x32_bf16(alf, bh, accL[nt], 0, 0, 0);
            bf16x8 ch = *(const bf16x8*)&whR[bofs];
            bf16x8 cl = *(const bf16x8*)&wlR[bofs];
            accR[nt] = __builtin_amdgcn_mfma_f32_16x16x32_bf16(ahf, ch, accR[nt], 0, 0, 0);
            accR[nt] = __builtin_amdgcn_mfma_f32_16x16x32_bf16(ahf, cl, accR[nt], 0, 0, 0);
            accR[nt] = __builtin_amdgcn_mfma_f32_16x16x32_bf16(alf, ch, accR[nt], 0, 0, 0);
        }
        __syncthreads();
    }

#pragma unroll
    for (int nt = 0; nt < 8; nt++) {
        int col = (nt >> 2) * 64 + (nt & 3) * 16 + lm;
#pragma unroll
        for (int r = 0; r < 4; r++) {
            int gr = row0 + m0 + quad * 4 + r;
            if (gr < M) {
                size_t o = (size_t)gr * DF + col;
                outL[o] = (_Float16)accL[nt][r];
                outR[o] = (_Float16)accR[nt][r];
            }
        }
    }
}

// ---------------------------------------------------------------------------
// Bin body: CSR pass 1 (coarse bucket sort).
// ---------------------------------------------------------------------------
__device__ __forceinline__ void bin_body(
    int bid, const int* __restrict__ ei,
    int* __restrict__ g_count, int* __restrict__ bucket_mem, char* smem_)
{
    int* cnt  = (int*)smem_;
    int* base = cnt + NB;
    int* cnt2 = base + NB;
    const int tid = threadIdx.x;

    for (int i = tid; i < NB; i += 256) { cnt[i] = 0; cnt2[i] = 0; }
    __syncthreads();

    const int e0 = bid * P1_CHUNK;
    int srcv[16], dstv[16];
#pragma unroll
    for (int i = 0; i < 16; i++) {
        int eid = e0 + i * 256 + tid;   // coalesced
        int s = 0, d = -1;
        if (eid < ET) {
            if (eid < N_EDGES) { s = ei[eid]; d = ei[N_EDGES + eid]; }
            else               { s = d = eid - N_EDGES; }
        }
        srcv[i] = s; dstv[i] = d;
        if (d >= 0) atomicAdd(&cnt[d >> 8], 1);
    }
    __syncthreads();
    for (int i = tid; i < NB; i += 256)
        base[i] = (cnt[i] > 0) ? atomicAdd(&g_count[i], cnt[i]) : 0;
    __syncthreads();
#pragma unroll
    for (int i = 0; i < 16; i++) {
        int d = dstv[i];
        if (d >= 0) {
            int b = d >> 8;
            int r = atomicAdd(&cnt2[b], 1);
            int slot = base[b] + r;
            if (slot < BCAP)
                bucket_mem[(size_t)b * BCAP + slot] =
                    (srcv[i] & 0xFFFF) | ((d & 255) << 16);
        }
    }
}

// ---------------------------------------------------------------------------
// Mega-dispatch: blocks [0, GEMM_BLOCKS) run layer-1 GEMM (fp32 input, reads
// pre-split Wh/Wl from wconv4); blocks [GEMM_BLOCKS, +BIN_BLOCKS) run the
// independent CSR bin pass. Overlap hides the bin cost under the GEMM.
// ---------------------------------------------------------------------------
__global__ __launch_bounds__(256) void gemm_bin(
    const float* __restrict__ X,
    const unsigned short* __restrict__ Wh, const unsigned short* __restrict__ Wl,
    _Float16* __restrict__ outL, _Float16* __restrict__ outR,
    const int* __restrict__ ei,
    int* __restrict__ g_count, int* __restrict__ bucket_mem)
{
    __shared__ char smem[51200];
    if (blockIdx.x < GEMM_BLOCKS)
        gemm_body<float>(blockIdx.x, X, Wh, Wl, Wh + 16384, Wl + 16384,
                         outL, outR, N_NODES, smem);
    else
        bin_body(blockIdx.x - GEMM_BLOCKS, ei, g_count, bucket_mem, smem);
}

// Layer-2 GEMM: fp16 input (layer-1 activations).
__global__ __launch_bounds__(256) void gemm_f16(
    const _Float16* __restrict__ X,
    const unsigned short* __restrict__ Wh, const unsigned short* __restrict__ Wl,
    _Float16* __restrict__ outL, _Float16* __restrict__ outR)
{
    __shared__ char smem[51200];
    gemm_body<_Float16>(blockIdx.x, X, Wh, Wl, Wh + 16384, Wl + 16384,
                        outL, outR, N_NODES, smem);
}

// ---------------------------------------------------------------------------
// CSR pass 2: one block per bucket (unchanged).
// ---------------------------------------------------------------------------
__global__ __launch_bounds__(256) void csr_pass(const int* __restrict__ g_count,
                                                const int* __restrict__ bucket_mem,
                                                int* __restrict__ row_ptr,
                                                unsigned short* __restrict__ csr_src)
{
    __shared__ int sh_edges[BCAP];
    __shared__ int hist[256], offs[256], excl[256], cnt2[256];
    __shared__ int gsc[256];
    const int b = blockIdx.x, tid = threadIdx.x;

    gsc[tid] = (tid < NB) ? g_count[tid] : 0;
    __syncthreads();
    for (int d = 1; d < 256; d <<= 1) {
        int x = (tid >= d) ? gsc[tid - d] : 0;
        __syncthreads();
        gsc[tid] += x;
        __syncthreads();
    }
    const int base_csr = (b > 0) ? gsc[b - 1] : 0;

    int m = g_count[b]; if (m > BCAP) m = BCAP;
    hist[tid] = 0; cnt2[tid] = 0;
    __syncthreads();
    const int* bm = bucket_mem + (size_t)b * BCAP;
    for (int i = tid; i < m; i += 256) {
        int p = bm[i];
        sh_edges[i] = p;
        atomicAdd(&hist[(p >> 16) & 255], 1);
    }
    __syncthreads();
    offs[tid] = hist[tid]; __syncthreads();
    for (int d = 1; d < 256; d <<= 1) {
        int x = (tid >= d) ? offs[tid - d] : 0;
        __syncthreads();
        offs[tid] += x;
        __syncthreads();
    }
    excl[tid] = offs[tid] - hist[tid];
    const int node0 = b << 8;
    if (node0 + tid < N_NODES) row_ptr[node0 + tid] = base_csr + excl[tid];
    if (b == 0 && tid == 0) row_ptr[N_NODES] = ET;
    __syncthreads();
    for (int i = tid; i < m; i += 256) {
        int p = sh_edges[i];
        int dl = (p >> 16) & 255;
        int r = atomicAdd(&cnt2[dl], 1);
        csr_src[base_csr + excl[dl] + r] = (unsigned short)(p & 0xFFFF);
    }
}

// ---------------------------------------------------------------------------
// Full-width fused scores + softmax + aggregate, 2-deep pipeline.
// One wave per node; 16 lanes/edge (8 fp16 ch/lane), 8 edges in flight.
// head = (l&15)>>2; logit via fdot2 + 2-shfl reduce; per-head den in-lane.
// TOut: layer-1 writes fp16 C, layer-2 writes fp32 d_out.
// ---------------------------------------------------------------------------
template<typename TOut>
__global__ __launch_bounds__(256) void fused_agg(
    const _Float16* __restrict__ XL, const _Float16* __restrict__ XR,
    const int* __restrict__ row_ptr, const unsigned short* __restrict__ csr_src,
    const float* __restrict__ att, const float* __restrict__ bias,
    TOut* __restrict__ out)
{
    const int t = threadIdx.x;
    const int wave = t >> 6, l = t & 63;
    const int g = l >> 4, gl = l & 15;       // edge group 0..3, lane in group
    const int n = blockIdx.x * 4 + wave;
    if (n >= N_NODES) return;
    const int beg = row_ptr[n], end = row_ptr[n + 1];

    const int c0 = gl * 8;                   // channels c0..c0+7
    half8 xrh = *(const half8*)(XR + (size_t)n * DF + c0);
    float4 at0 = *(const float4*)(att + c0);
    float4 at1 = *(const float4*)(att + c0 + 4);
    half2v a01 = { (_Float16)at0.x, (_Float16)at0.y };
    half2v a23 = { (_Float16)at0.z, (_Float16)at0.w };
    half2v a45 = { (_Float16)at1.x, (_Float16)at1.y };
    half2v a67 = { (_Float16)at1.z, (_Float16)at1.w };
    const half8 slp = { (_Float16)SLOPE, (_Float16)SLOPE, (_Float16)SLOPE, (_Float16)SLOPE,
                        (_Float16)SLOPE, (_Float16)SLOPE, (_Float16)SLOPE, (_Float16)SLOPE };

    float a0 = 0.f, a1 = 0.f, a2 = 0.f, a3 = 0.f;
    float a4 = 0.f, a5 = 0.f, a6 = 0.f, a7 = 0.f, den = 0.f;

    // pipeline prologue: two octets in flight
    int e0i = beg + g;
    int s0 = (e0i < end) ? csr_src[e0i] : 0;
    half8 hv0 = *(const half8*)(XL + (size_t)s0 * DF + c0);
    int e1i = beg + 4 + g;
    int s1 = (e1i < end) ? csr_src[e1i] : 0;
    half8 hv1 = *(const half8*)(XL + (size_t)s1 * DF + c0);

#define EDGE_STEP(HV, EOK)                                                     \
    {                                                                          \
        half8 msg = HV + xrh;                                                  \
        half8 lk  = __builtin_elementwise_max(msg, msg * slp);                 \
        half2v m01 = { lk[0], lk[1] };                                         \
        half2v m23 = { lk[2], lk[3] };                                         \
        half2v m45 = { lk[4], lk[5] };                                         \
        half2v m67 = { lk[6], lk[7] };                                         \
        float p = __builtin_amdgcn_fdot2(m01, a01, 0.f, false);                \
        p = __builtin_amdgcn_fdot2(m23, a23, p, false);                        \
        p = __builtin_amdgcn_fdot2(m45, a45, p, false);                        \
        p = __builtin_amdgcn_fdot2(m67, a67, p, false);                        \
        p += __shfl_xor(p, 1);                                                 \
        p += __shfl_xor(p, 2);                                                 \
        float e = (EOK) ? __expf(p) : 0.f;                                     \
        a0 += e * (float)HV[0]; a1 += e * (float)HV[1];                        \
        a2 += e * (float)HV[2]; a3 += e * (float)HV[3];                        \
        a4 += e * (float)HV[4]; a5 += e * (float)HV[5];                        \
        a6 += e * (float)HV[6]; a7 += e * (float)HV[7];                        \
        den += e;                                                              \
    }

    for (int j = beg; j < end; j += 8) {
        // prefetch the next two octets (row-0 fallback, branchless)
        int en0 = j + 8 + g;
        int sn0 = (en0 < end) ? csr_src[en0] : 0;
        half8 hn0 = *(const half8*)(XL + (size_t)sn0 * DF + c0);
        int en1 = j + 12 + g;
        int sn1 = (en1 < end) ? csr_src[en1] : 0;
        half8 hn1 = *(const half8*)(XL + (size_t)sn1 * DF + c0);

        EDGE_STEP(hv0, (j + g < end))
        EDGE_STEP(hv1, (j + 4 + g < end))

        hv0 = hn0; hv1 = hn1;
    }
#undef EDGE_STEP

    // combine the 4 edge-group accumulators (l bits 4-5)
#define CMB(x) x += __shfl_xor(x, 16); x += __shfl_xor(x, 32);
    CMB(a0) CMB(a1) CMB(a2) CMB(a3) CMB(a4) CMB(a5) CMB(a6) CMB(a7) CMB(den)
#undef CMB

    if (g == 0) {
        float inv = 1.f / (den + 1e-16f);     // den is this lane's head's total
        float4 b0 = *(const float4*)(bias + c0);
        float4 b1 = *(const float4*)(bias + c0 + 4);
        float o[8];
        o[0] = fmaxf(a0 * inv + b0.x, 0.f);
        o[1] = fmaxf(a1 * inv + b0.y, 0.f);
        o[2] = fmaxf(a2 * inv + b0.z, 0.f);
        o[3] = fmaxf(a3 * inv + b0.w, 0.f);
        o[4] = fmaxf(a4 * inv + b1.x, 0.f);
        o[5] = fmaxf(a5 * inv + b1.y, 0.f);
        o[6] = fmaxf(a6 * inv + b1.z, 0.f);
        o[7] = fmaxf(a7 * inv + b1.w, 0.f);
        TOut* op = out + (size_t)n * DF + c0;
        if constexpr (sizeof(TOut) == 2) {
            half8 hv;
#pragma unroll
            for (int i = 0; i < 8; i++) hv[i] = (_Float16)o[i];
            *(half8*)op = hv;
        } else {
            *(float4*)(op)     = make_float4(o[0], o[1], o[2], o[3]);
            *(float4*)(op + 4) = make_float4(o[4], o[5], o[6], o[7]);
        }
    }
}

// ---------------------------------------------------------------------------
extern "C" void kernel_launch(void* const* d_in, const int* in_sizes, int n_in,
                              void* d_out, int out_size, void* d_ws, size_t ws_size,
                              hipStream_t stream)
{
    (void)in_sizes; (void)n_in; (void)out_size; (void)ws_size;

    const float* x    = (const float*)d_in[0];
    const int*   ei   = (const int*)d_in[1];
    const float* W1l  = (const float*)d_in[2];
    const float* W1r  = (const float*)d_in[3];
    const float* att1 = (const float*)d_in[4];
    const float* b1   = (const float*)d_in[5];
    const float* W2l  = (const float*)d_in[6];
    const float* W2r  = (const float*)d_in[7];
    const float* att2 = (const float*)d_in[8];
    const float* b2   = (const float*)d_in[9];
    float* out = (float*)d_out;

    char* ws = (char*)d_ws;
    size_t off = 0;
    const size_t NF = (size_t)N_NODES * DF * sizeof(float);        // 25.6 MB
    _Float16* A = (_Float16*)(ws + off); off += NF / 2;            // xl fp16 [N][128]
    _Float16* B = (_Float16*)(ws + off); off += NF / 2;            // xr fp16 [N][128]
    _Float16* C = (_Float16*)(ws + off); off += NF / 2;            // layer-1 out fp16
    int* bucket_mem  = (int*)(ws + off); off += (size_t)NB * BCAP * sizeof(int);
    int* g_count     = (int*)(ws + off); off += 256 * sizeof(int);
    int* row_ptr     = (int*)(ws + off); off += (size_t)(N_NODES + 1) * sizeof(int);
    unsigned short* csr_src = (unsigned short*)(ws + off);
    off += ((size_t)ET * sizeof(unsigned short) + 255) & ~(size_t)255;
    unsigned short* Wh = (unsigned short*)(ws + off); off += 4 * 16384 * sizeof(unsigned short);
    unsigned short* Wl = (unsigned short*)(ws + off); off += 4 * 16384 * sizeof(unsigned short);

    // ---- one-time prep: W split (also zeroes g_count) ----
    wconv4<<<256, 256, 0, stream>>>(W1l, W1r, W2l, W2r, Wh, Wl, g_count);

    // ---- layer-1 GEMM + CSR bin pass, overlapped in one dispatch ----
    gemm_bin<<<GEMM_BLOCKS + BIN_BLOCKS, 256, 0, stream>>>(
        x, Wh, Wl, A, B, ei, g_count, bucket_mem);
    csr_pass<<<NB, 256, 0, stream>>>(g_count, bucket_mem, row_ptr, csr_src);
    fused_agg<_Float16><<<(N_NODES + 3) / 4, 256, 0, stream>>>(
        A, B, row_ptr, csr_src, att1, b1, C);

    // ---- layer 2 ----
    gemm_f16<<<GEMM_BLOCKS, 256, 0, stream>>>(C, Wh + 2 * 16384, Wl + 2 * 16384, A, B);
    fused_agg<float><<<(N_NODES + 3) / 4, 256, 0, stream>>>(
        A, B, row_ptr, csr_src, att2, b2, out);
}

// Round 13
// 276.567 us; speedup vs baseline: 1.2698x; 1.0382x over previous
//
#include <hip/hip_runtime.h>

#define N_NODES 50000
#define N_EDGES 1600000
#define ET (N_EDGES + N_NODES)   // edges + self-loops
#define DF 128                   // feature / hidden dim
#define SLOPE 0.2f

#define NB 196        // coarse buckets: dst >> 8 (50000/256)
#define BCAP 10240    // slots per bucket (avg 8448, sigma ~92 -> +19 sigma)
#define P1_CHUNK 4096 // edges per bin block (16 per thread)
#define GEMM_BLOCKS ((N_NODES + 63) / 64)            // 782
#define BIN_BLOCKS ((ET + P1_CHUNK - 1) / P1_CHUNK)  // 403

typedef __attribute__((ext_vector_type(4))) float floatx4;     // MFMA C/D
typedef __attribute__((ext_vector_type(8))) _Float16 half8;    // 8 fp16 (16 B)
typedef __attribute__((ext_vector_type(2))) _Float16 half2v;   // fdot2 operand

// ---------------------------------------------------------------------------
// One-time W prep (also zeroes g_count). Splits the four 128x128 W matrices
// into fp16 hi + fp16 residual lo, stored TRANSPOSED [c][k].
// fp16 hi/lo: ~21 mantissa bits if lo survives (residuals are subnormal-range;
// if MFMA flushes them, W error = fp16 RNE 4.9e-4 rel -- absmax-checked).
// ---------------------------------------------------------------------------
__global__ __launch_bounds__(256) void wconv4(
    const float* __restrict__ W0, const float* __restrict__ W1,
    const float* __restrict__ W2, const float* __restrict__ W3,
    _Float16* __restrict__ Wh, _Float16* __restrict__ Wl,
    int* __restrict__ g_count)
{
    if (blockIdx.x == 0) g_count[threadIdx.x] = 0;
    int idx = blockIdx.x * 256 + threadIdx.x;   // 0..65535
    int m = idx >> 14, rem = idx & 16383;
    const float* W = (m == 0) ? W0 : (m == 1) ? W1 : (m == 2) ? W2 : W3;
    int c = rem >> 7, k = rem & 127;
    float v = W[k * 128 + c];
    _Float16 h = (_Float16)v;
    Wh[(size_t)m * 16384 + c * 128 + k] = h;
    Wl[(size_t)m * 16384 + c * 128 + k] = (_Float16)(v - (float)h);
}

__device__ __forceinline__ half8 load_h8(const float* p) {
    float4 a = *(const float4*)(p);
    float4 b = *(const float4*)(p + 4);
    half8 h;
    h[0] = (_Float16)a.x; h[1] = (_Float16)a.y;
    h[2] = (_Float16)a.z; h[3] = (_Float16)a.w;
    h[4] = (_Float16)b.x; h[5] = (_Float16)b.y;
    h[6] = (_Float16)b.z; h[7] = (_Float16)b.w;
    return h;
}
__device__ __forceinline__ half8 load_h8(const _Float16* p) {
    return *(const half8*)p;
}

// ---------------------------------------------------------------------------
// GEMM body: fp16 MFMA, L+R merged, 64-row tile, BK=32, 32 MFMA/K-iter.
// acc = X16*Wh + X16*Wl. X staged as fp16 (layer 2: raw copy, zero cvt).
// Outputs fp16 standard [M][128]. LDS 46 KB -> 3 blocks/CU.
// ---------------------------------------------------------------------------
template<typename T>
__device__ __forceinline__ void gemm_body(
    int bid, const T* __restrict__ X,
    const _Float16* __restrict__ WhL, const _Float16* __restrict__ WlL,
    const _Float16* __restrict__ WhR, const _Float16* __restrict__ WlR,
    _Float16* __restrict__ outL, _Float16* __restrict__ outR, int M, char* smem_)
{
    _Float16* xs  = (_Float16*)smem_;      // 64*40  (5,120 B)
    _Float16* whL = xs + 64 * 40;          // 128*40 (10,240 B each)
    _Float16* wlL = whL + 128 * 40;
    _Float16* whR = wlL + 128 * 40;
    _Float16* wlR = whR + 128 * 40;        // total 46,080 B

    const int t = threadIdx.x;
    const int row0 = bid * 64;
    const int lane = t & 63, wv = t >> 6;
    const int lm = lane & 15, quad = lane >> 4;
    const int m0 = wv * 16;

    floatx4 accL[8], accR[8];
#pragma unroll
    for (int i = 0; i < 8; i++) { accL[i] = (floatx4)0.f; accR[i] = (floatx4)0.f; }

    const int sr = t >> 2;          // X stage: row 0..63 (4 thr/row)
    const int sc = (t & 3) * 8;     // X stage: k offset
    const int wn = t >> 1;          // W stage: col 0..127 (2 thr/col)
    const int wkh = (t & 1) * 16;   // W stage: k half

    for (int kb = 0; kb < 128; kb += 32) {
        int xrow = row0 + sr; if (xrow >= M) xrow = M - 1;
        half8 xv = load_h8(X + (size_t)xrow * DF + kb + sc);
        *(half8*)&xs[sr * 40 + sc] = xv;

        const size_t wofs = (size_t)wn * 128 + kb + wkh;
        {
            const uint4* p = (const uint4*)(WhL + wofs);
            uint4 a = p[0], b = p[1];
            *(uint4*)&whL[wn * 40 + wkh] = a; *(uint4*)&whL[wn * 40 + wkh + 8] = b;
        }
        {
            const uint4* p = (const uint4*)(WlL + wofs);
            uint4 a = p[0], b = p[1];
            *(uint4*)&wlL[wn * 40 + wkh] = a; *(uint4*)&wlL[wn * 40 + wkh + 8] = b;
        }
        {
            const uint4* p = (const uint4*)(WhR + wofs);
            uint4 a = p[0], b = p[1];
            *(uint4*)&whR[wn * 40 + wkh] = a; *(uint4*)&whR[wn * 40 + wkh + 8] = b;
        }
        {
            const uint4* p = (const uint4*)(WlR + wofs);
            uint4 a = p[0], b = p[1];
            *(uint4*)&wlR[wn * 40 + wkh] = a; *(uint4*)&wlR[wn * 40 + wkh + 8] = b;
        }
        __syncthreads();

        half8 af = *(const half8*)&xs[(m0 + lm) * 40 + quad * 8];
#pragma unroll
        for (int nt = 0; nt < 8; nt++) {
            const int bofs = (nt * 16 + lm) * 40 + quad * 8;
            half8 bh = *(const half8*)&whL[bofs];
            half8 bl = *(const half8*)&wlL[bofs];
            accL[nt] = __builtin_amdgcn_mfma_f32_16x16x32_f16(af, bh, accL[nt], 0, 0, 0);
            accL[nt] = __builtin_amdgcn_mfma_f32_16x16x32_f16(af, bl, accL[nt], 0, 0, 0);
            half8 ch = *(const half8*)&whR[bofs];
            half8 cl = *(const half8*)&wlR[bofs];
            accR[nt] = __builtin_amdgcn_mfma_f32_16x16x32_f16(af, ch, accR[nt], 0, 0, 0);
            accR[nt] = __builtin_amdgcn_mfma_f32_16x16x32_f16(af, cl, accR[nt], 0, 0, 0);
        }
        __syncthreads();
    }

#pragma unroll
    for (int nt = 0; nt < 8; nt++) {
        int col = (nt >> 2) * 64 + (nt & 3) * 16 + lm;
#pragma unroll
        for (int r = 0; r < 4; r++) {
            int gr = row0 + m0 + quad * 4 + r;
            if (gr < M) {
                size_t o = (size_t)gr * DF + col;
                outL[o] = (_Float16)accL[nt][r];
                outR[o] = (_Float16)accR[nt][r];
            }
        }
    }
}

// ---------------------------------------------------------------------------
// Bin body: CSR pass 1 (coarse bucket sort).
// ---------------------------------------------------------------------------
__device__ __forceinline__ void bin_body(
    int bid, const int* __restrict__ ei,
    int* __restrict__ g_count, int* __restrict__ bucket_mem, char* smem_)
{
    int* cnt  = (int*)smem_;
    int* base = cnt + NB;
    int* cnt2 = base + NB;
    const int tid = threadIdx.x;

    for (int i = tid; i < NB; i += 256) { cnt[i] = 0; cnt2[i] = 0; }
    __syncthreads();

    const int e0 = bid * P1_CHUNK;
    int srcv[16], dstv[16];
#pragma unroll
    for (int i = 0; i < 16; i++) {
        int eid = e0 + i * 256 + tid;   // coalesced
        int s = 0, d = -1;
        if (eid < ET) {
            if (eid < N_EDGES) { s = ei[eid]; d = ei[N_EDGES + eid]; }
            else               { s = d = eid - N_EDGES; }
        }
        srcv[i] = s; dstv[i] = d;
        if (d >= 0) atomicAdd(&cnt[d >> 8], 1);
    }
    __syncthreads();
    for (int i = tid; i < NB; i += 256)
        base[i] = (cnt[i] > 0) ? atomicAdd(&g_count[i], cnt[i]) : 0;
    __syncthreads();
#pragma unroll
    for (int i = 0; i < 16; i++) {
        int d = dstv[i];
        if (d >= 0) {
            int b = d >> 8;
            int r = atomicAdd(&cnt2[b], 1);
            int slot = base[b] + r;
            if (slot < BCAP)
                bucket_mem[(size_t)b * BCAP + slot] =
                    (srcv[i] & 0xFFFF) | ((d & 255) << 16);
        }
    }
}

// ---------------------------------------------------------------------------
// Mega-dispatch: blocks [0, GEMM_BLOCKS) = layer-1 GEMM (fp32 input, reads
// pre-split Wh/Wl); blocks [GEMM_BLOCKS, +BIN_BLOCKS) = CSR bin pass.
// ---------------------------------------------------------------------------
__global__ __launch_bounds__(256) void gemm_bin(
    const float* __restrict__ X,
    const _Float16* __restrict__ Wh, const _Float16* __restrict__ Wl,
    _Float16* __restrict__ outL, _Float16* __restrict__ outR,
    const int* __restrict__ ei,
    int* __restrict__ g_count, int* __restrict__ bucket_mem)
{
    __shared__ char smem[46080];
    if (blockIdx.x < GEMM_BLOCKS)
        gemm_body<float>(blockIdx.x, X, Wh, Wl, Wh + 16384, Wl + 16384,
                         outL, outR, N_NODES, smem);
    else
        bin_body(blockIdx.x - GEMM_BLOCKS, ei, g_count, bucket_mem, smem);
}

// Layer-2 GEMM: fp16 input (layer-1 activations; zero-cvt staging).
__global__ __launch_bounds__(256) void gemm_f16(
    const _Float16* __restrict__ X,
    const _Float16* __restrict__ Wh, const _Float16* __restrict__ Wl,
    _Float16* __restrict__ outL, _Float16* __restrict__ outR)
{
    __shared__ char smem[46080];
    gemm_body<_Float16>(blockIdx.x, X, Wh, Wl, Wh + 16384, Wl + 16384,
                        outL, outR, N_NODES, smem);
}

// ---------------------------------------------------------------------------
// CSR pass 2: one block per bucket, 1024 threads (4x fewer serial iters).
// Scan phases use threads 0..255; edge loops use all 1024.
// ---------------------------------------------------------------------------
__global__ __launch_bounds__(1024) void csr_pass(const int* __restrict__ g_count,
                                                 const int* __restrict__ bucket_mem,
                                                 int* __restrict__ row_ptr,
                                                 unsigned short* __restrict__ csr_src)
{
    __shared__ int sh_edges[BCAP];
    __shared__ int hist[256], offs[256], excl[256], cnt2[256];
    __shared__ int gsc[256];
    const int b = blockIdx.x, tid = threadIdx.x;

    if (tid < 256) gsc[tid] = (tid < NB) ? g_count[tid] : 0;
    __syncthreads();
    for (int d = 1; d < 256; d <<= 1) {
        int x = 0;
        if (tid < 256 && tid >= d) x = gsc[tid - d];
        __syncthreads();
        if (tid < 256) gsc[tid] += x;
        __syncthreads();
    }
    const int base_csr = (b > 0) ? gsc[b - 1] : 0;

    int m = g_count[b]; if (m > BCAP) m = BCAP;
    if (tid < 256) { hist[tid] = 0; cnt2[tid] = 0; }
    __syncthreads();
    const int* bm = bucket_mem + (size_t)b * BCAP;
    for (int i = tid; i < m; i += 1024) {
        int p = bm[i];
        sh_edges[i] = p;
        atomicAdd(&hist[(p >> 16) & 255], 1);
    }
    __syncthreads();
    if (tid < 256) offs[tid] = hist[tid];
    __syncthreads();
    for (int d = 1; d < 256; d <<= 1) {
        int x = 0;
        if (tid < 256 && tid >= d) x = offs[tid - d];
        __syncthreads();
        if (tid < 256) offs[tid] += x;
        __syncthreads();
    }
    if (tid < 256) {
        excl[tid] = offs[tid] - hist[tid];
        int node = (b << 8) + tid;
        if (node < N_NODES) row_ptr[node] = base_csr + excl[tid];
    }
    if (b == 0 && tid == 0) row_ptr[N_NODES] = ET;
    __syncthreads();
    for (int i = tid; i < m; i += 1024) {
        int p = sh_edges[i];
        int dl = (p >> 16) & 255;
        int r = atomicAdd(&cnt2[dl], 1);
        csr_src[base_csr + excl[dl] + r] = (unsigned short)(p & 0xFFFF);
    }
}

// ---------------------------------------------------------------------------
// Full-width fused scores + softmax + aggregate, 2-deep pipeline (unchanged
// from R12 -- measured service-bound at ~62 us).
// ---------------------------------------------------------------------------
template<typename TOut>
__global__ __launch_bounds__(256) void fused_agg(
    const _Float16* __restrict__ XL, const _Float16* __restrict__ XR,
    const int* __restrict__ row_ptr, const unsigned short* __restrict__ csr_src,
    const float* __restrict__ att, const float* __restrict__ bias,
    TOut* __restrict__ out)
{
    const int t = threadIdx.x;
    const int wave = t >> 6, l = t & 63;
    const int g = l >> 4, gl = l & 15;       // edge group 0..3, lane in group
    const int n = blockIdx.x * 4 + wave;
    if (n >= N_NODES) return;
    const int beg = row_ptr[n], end = row_ptr[n + 1];

    const int c0 = gl * 8;                   // channels c0..c0+7
    half8 xrh = *(const half8*)(XR + (size_t)n * DF + c0);
    float4 at0 = *(const float4*)(att + c0);
    float4 at1 = *(const float4*)(att + c0 + 4);
    half2v a01 = { (_Float16)at0.x, (_Float16)at0.y };
    half2v a23 = { (_Float16)at0.z, (_Float16)at0.w };
    half2v a45 = { (_Float16)at1.x, (_Float16)at1.y };
    half2v a67 = { (_Float16)at1.z, (_Float16)at1.w };
    const half8 slp = { (_Float16)SLOPE, (_Float16)SLOPE, (_Float16)SLOPE, (_Float16)SLOPE,
                        (_Float16)SLOPE, (_Float16)SLOPE, (_Float16)SLOPE, (_Float16)SLOPE };

    float a0 = 0.f, a1 = 0.f, a2 = 0.f, a3 = 0.f;
    float a4 = 0.f, a5 = 0.f, a6 = 0.f, a7 = 0.f, den = 0.f;

    // pipeline prologue: two octets in flight
    int e0i = beg + g;
    int s0 = (e0i < end) ? csr_src[e0i] : 0;
    half8 hv0 = *(const half8*)(XL + (size_t)s0 * DF + c0);
    int e1i = beg + 4 + g;
    int s1 = (e1i < end) ? csr_src[e1i] : 0;
    half8 hv1 = *(const half8*)(XL + (size_t)s1 * DF + c0);

#define EDGE_STEP(HV, EOK)                                                     \
    {                                                                          \
        half8 msg = HV + xrh;                                                  \
        half8 lk  = __builtin_elementwise_max(msg, msg * slp);                 \
        half2v m01 = { lk[0], lk[1] };                                         \
        half2v m23 = { lk[2], lk[3] };                                         \
        half2v m45 = { lk[4], lk[5] };                                         \
        half2v m67 = { lk[6], lk[7] };                                         \
        float p = __builtin_amdgcn_fdot2(m01, a01, 0.f, false);                \
        p = __builtin_amdgcn_fdot2(m23, a23, p, false);                        \
        p = __builtin_amdgcn_fdot2(m45, a45, p, false);                        \
        p = __builtin_amdgcn_fdot2(m67, a67, p, false);                        \
        p += __shfl_xor(p, 1);                                                 \
        p += __shfl_xor(p, 2);                                                 \
        float e = (EOK) ? __expf(p) : 0.f;                                     \
        a0 += e * (float)HV[0]; a1 += e * (float)HV[1];                        \
        a2 += e * (float)HV[2]; a3 += e * (float)HV[3];                        \
        a4 += e * (float)HV[4]; a5 += e * (float)HV[5];                        \
        a6 += e * (float)HV[6]; a7 += e * (float)HV[7];                        \
        den += e;                                                              \
    }

    for (int j = beg; j < end; j += 8) {
        int en0 = j + 8 + g;
        int sn0 = (en0 < end) ? csr_src[en0] : 0;
        half8 hn0 = *(const half8*)(XL + (size_t)sn0 * DF + c0);
        int en1 = j + 12 + g;
        int sn1 = (en1 < end) ? csr_src[en1] : 0;
        half8 hn1 = *(const half8*)(XL + (size_t)sn1 * DF + c0);

        EDGE_STEP(hv0, (j + g < end))
        EDGE_STEP(hv1, (j + 4 + g < end))

        hv0 = hn0; hv1 = hn1;
    }
#undef EDGE_STEP

#define CMB(x) x += __shfl_xor(x, 16); x += __shfl_xor(x, 32);
    CMB(a0) CMB(a1) CMB(a2) CMB(a3) CMB(a4) CMB(a5) CMB(a6) CMB(a7) CMB(den)
#undef CMB

    if (g == 0) {
        float inv = 1.f / (den + 1e-16f);     // den is this lane's head's total
        float4 b0 = *(const float4*)(bias + c0);
        float4 b1 = *(const float4*)(bias + c0 + 4);
        float o[8];
        o[0] = fmaxf(a0 * inv + b0.x, 0.f);
        o[1] = fmaxf(a1 * inv + b0.y, 0.f);
        o[2] = fmaxf(a2 * inv + b0.z, 0.f);
        o[3] = fmaxf(a3 * inv + b0.w, 0.f);
        o[4] = fmaxf(a4 * inv + b1.x, 0.f);
        o[5] = fmaxf(a5 * inv + b1.y, 0.f);
        o[6] = fmaxf(a6 * inv + b1.z, 0.f);
        o[7] = fmaxf(a7 * inv + b1.w, 0.f);
        TOut* op = out + (size_t)n * DF + c0;
        if constexpr (sizeof(TOut) == 2) {
            half8 hv;
#pragma unroll
            for (int i = 0; i < 8; i++) hv[i] = (_Float16)o[i];
            *(half8*)op = hv;
        } else {
            *(float4*)(op)     = make_float4(o[0], o[1], o[2], o[3]);
            *(float4*)(op + 4) = make_float4(o[4], o[5], o[6], o[7]);
        }
    }
}

// ---------------------------------------------------------------------------
extern "C" void kernel_launch(void* const* d_in, const int* in_sizes, int n_in,
                              void* d_out, int out_size, void* d_ws, size_t ws_size,
                              hipStream_t stream)
{
    (void)in_sizes; (void)n_in; (void)out_size; (void)ws_size;

    const float* x    = (const float*)d_in[0];
    const int*   ei   = (const int*)d_in[1];
    const float* W1l  = (const float*)d_in[2];
    const float* W1r  = (const float*)d_in[3];
    const float* att1 = (const float*)d_in[4];
    const float* b1   = (const float*)d_in[5];
    const float* W2l  = (const float*)d_in[6];
    const float* W2r  = (const float*)d_in[7];
    const float* att2 = (const float*)d_in[8];
    const float* b2   = (const float*)d_in[9];
    float* out = (float*)d_out;

    char* ws = (char*)d_ws;
    size_t off = 0;
    const size_t NF = (size_t)N_NODES * DF * sizeof(float);        // 25.6 MB
    _Float16* A = (_Float16*)(ws + off); off += NF / 2;            // xl fp16 [N][128]
    _Float16* B = (_Float16*)(ws + off); off += NF / 2;            // xr fp16 [N][128]
    _Float16* C = (_Float16*)(ws + off); off += NF / 2;            // layer-1 out fp16
    int* bucket_mem  = (int*)(ws + off); off += (size_t)NB * BCAP * sizeof(int);
    int* g_count     = (int*)(ws + off); off += 256 * sizeof(int);
    int* row_ptr     = (int*)(ws + off); off += (size_t)(N_NODES + 1) * sizeof(int);
    unsigned short* csr_src = (unsigned short*)(ws + off);
    off += ((size_t)ET * sizeof(unsigned short) + 255) & ~(size_t)255;
    _Float16* Wh = (_Float16*)(ws + off); off += 4 * 16384 * sizeof(_Float16);
    _Float16* Wl = (_Float16*)(ws + off); off += 4 * 16384 * sizeof(_Float16);

    // ---- one-time prep: W split (also zeroes g_count) ----
    wconv4<<<256, 256, 0, stream>>>(W1l, W1r, W2l, W2r, Wh, Wl, g_count);

    // ---- layer-1 GEMM + CSR bin pass, overlapped in one dispatch ----
    gemm_bin<<<GEMM_BLOCKS + BIN_BLOCKS, 256, 0, stream>>>(
        x, Wh, Wl, A, B, ei, g_count, bucket_mem);
    csr_pass<<<NB, 1024, 0, stream>>>(g_count, bucket_mem, row_ptr, csr_src);
    fused_agg<_Float16><<<(N_NODES + 3) / 4, 256, 0, stream>>>(
        A, B, row_ptr, csr_src, att1, b1, C);

    // ---- layer 2 ----
    gemm_f16<<<GEMM_BLOCKS, 256, 0, stream>>>(C, Wh + 2 * 16384, Wl + 2 * 16384, A, B);
    fused_agg<float><<<(N_NODES + 3) / 4, 256, 0, stream>>>(
        A, B, row_ptr, csr_src, att2, b2, out);
}